// Round 7
// baseline (266.289 us; speedup 1.0000x reference)
//
#include <hip/hip_runtime.h>

#define N_NODES 100000
#define NT (2 * N_NODES)             // stacked nodes (conv1 then conv2)
#define D 128
#define N_EDGES 600000
#define ET (2 * N_EDGES)
#define SCAN_B 256
#define NBLK2 ((NT + SCAN_B - 1) / SCAN_B)   // 782
#define FROWS 256                            // rows per fused block (16 waves)
#define FBLK ((N_NODES + FROWS - 1) / FROWS) // 391

typedef __attribute__((ext_vector_type(8))) short bf16x8;
typedef __attribute__((ext_vector_type(4))) float f32x4;

__device__ __forceinline__ unsigned short f2bf(float f) {
    union { float f; unsigned u; } v; v.f = f;
    unsigned r = (v.u + 0x7fff + ((v.u >> 16) & 1)) >> 16;   // RNE
    return (unsigned short)r;
}
__device__ __forceinline__ float bf2f(unsigned short h) {
    union { unsigned u; float f; } v; v.u = ((unsigned)h) << 16;
    return v.f;
}

// ---------- edge index dtype handling ----------
__device__ __forceinline__ long long load_idx(const void* e, long long i, int is32) {
    if (is32) return (long long)((const int*)e)[i];
    return ((const long long*)e)[i];
}

// parallel detect: 64 lanes sample, ballot
__global__ void detect_kernel(const unsigned long long* __restrict__ e, int* __restrict__ flag) {
    unsigned long long v = e[threadIdx.x];
    unsigned long long m = __ballot(v > 0xFFFFFFFFull);
    if (threadIdx.x == 0) *flag = (m != 0ull) ? 1 : 0;
}

// ---------- merged prep: blocks 0..127 -> Mt, block 128 -> bt ----------
// Mt[j][k] bf16: j=out col (128), k=stacked contraction (256)
__global__ void prep_weights(const float* __restrict__ W1, const float* __restrict__ W2,
                             const float* __restrict__ weight,
                             const float* __restrict__ b1, const float* __restrict__ b2,
                             const float* __restrict__ bias,
                             unsigned short* __restrict__ Mt, float* __restrict__ bt) {
    if (blockIdx.x < 128) {
        int idx = blockIdx.x * 256 + threadIdx.x;   // 128*256
        int j = idx >> 8, k = idx & 255;
        float a = 0.f;
        if (k < D) {
            for (int d = 0; d < D; ++d) a += W1[k * D + d] * weight[d * D + j];
        } else {
            for (int d = 0; d < D; ++d) a += W2[(k - D) * D + d] * weight[(D + d) * D + j];
        }
        Mt[j * 256 + k] = f2bf(a);
    } else {
        int j = threadIdx.x;
        if (j >= D) return;
        float a = bias[j];
        for (int k = 0; k < D; ++k)
            a += b1[k] * weight[k * D + j] + b2[k] * weight[(D + k) * D + j];
        bt[j] = a;
    }
}

// ---------- merged: x->bf16 convert (blocks 0..12499) + degree histogram (rest) ----------
__global__ void x2bf_degree(const float* __restrict__ x, unsigned short* __restrict__ xb,
                            const void* __restrict__ ep, const void* __restrict__ en,
                            const int* __restrict__ flag, int* __restrict__ degi) {
    if (blockIdx.x < 12500) {
        long long t = (long long)blockIdx.x * 256 + threadIdx.x;   // N*32 float4 slots
        float4 a = ((const float4*)x)[t];
        ((ushort4*)xb)[t] = make_ushort4(f2bf(a.x), f2bf(a.y), f2bf(a.z), f2bf(a.w));
    } else {
        int i = (blockIdx.x - 12500) * 256 + threadIdx.x;
        if (i >= ET) return;
        int is32 = *flag;
        int conv = (i >= N_EDGES);
        const void* e = conv ? en : ep;
        int j = conv ? i - N_EDGES : i;
        long long d = load_idx(e, (long long)N_EDGES + j, is32);
        atomicAdd(&degi[conv * N_NODES + (int)d], 1);
    }
}

// ---------- scan pass1 over NT (+ fused dinv) ----------
__global__ void scan_pass1(const int* __restrict__ degi, int* __restrict__ bsum,
                           float* __restrict__ dinv) {
    __shared__ int sm[SCAN_B];
    int i = blockIdx.x * SCAN_B + threadIdx.x;
    int v = (i < NT) ? degi[i] : 0;
    if (i < NT) dinv[i] = rsqrtf((float)v + 1.0f);
    sm[threadIdx.x] = v;
    __syncthreads();
    for (int s = SCAN_B / 2; s > 0; s >>= 1) {
        if (threadIdx.x < s) sm[threadIdx.x] += sm[threadIdx.x + s];
        __syncthreads();
    }
    if (threadIdx.x == 0) bsum[blockIdx.x] = sm[0];
}

__global__ void scan_pass2(int* __restrict__ bsum) {   // single block of 1024
    __shared__ int sm[1024];
    int t = threadIdx.x;
    int v = (t < NBLK2) ? bsum[t] : 0;
    sm[t] = v;
    __syncthreads();
    for (int ofs = 1; ofs < 1024; ofs <<= 1) {
        int add = (t >= ofs) ? sm[t - ofs] : 0;
        __syncthreads();
        sm[t] += add;
        __syncthreads();
    }
    if (t < NBLK2) bsum[t] = sm[t] - v;   // exclusive
}

__global__ void scan_pass3(const int* __restrict__ degi, const int* __restrict__ bsum,
                           int* __restrict__ off) {
    __shared__ int sm[SCAN_B];
    int i = blockIdx.x * SCAN_B + threadIdx.x;
    int v = (i < NT) ? degi[i] : 0;
    sm[threadIdx.x] = v;
    __syncthreads();
    for (int ofs = 1; ofs < SCAN_B; ofs <<= 1) {
        int add = (threadIdx.x >= ofs) ? sm[threadIdx.x - ofs] : 0;
        __syncthreads();
        sm[threadIdx.x] += add;
        __syncthreads();
    }
    int excl = sm[threadIdx.x] - v + bsum[blockIdx.x];
    if (i < NT) off[i] = excl;
    if (i == NT - 1) off[NT] = excl + v;
}

// ---------- CSR fill (both convs), stores {src_row, coef}; degi used as countdown ----------
__global__ void csr_fill_both(const void* __restrict__ ep, const void* __restrict__ en,
                              const int* __restrict__ flag, const int* __restrict__ off,
                              int* __restrict__ degi, const float* __restrict__ dinv,
                              int2* __restrict__ csr) {
    int i = blockIdx.x * blockDim.x + threadIdx.x;
    if (i >= ET) return;
    int is32 = *flag;
    int conv = (i >= N_EDGES);
    const void* e = conv ? en : ep;
    int j = conv ? i - N_EDGES : i;
    int si = (int)load_idx(e, j, is32);
    int di = (int)load_idx(e, (long long)N_EDGES + j, is32);
    int g = conv * N_NODES;
    int node = g + di;
    int pos = off[node] + atomicSub(&degi[node], 1) - 1;   // countdown: positions deg-1..0
    float coef = dinv[g + si] * dinv[node];
    csr[pos] = make_int2(si, __float_as_int(coef));
}

// ---------- fused gather + GEMM ----------
// 1024 threads = 16 waves; wave w owns output rows [blk*256 + 16w, +16).
// Lane l (rl=l&15, q=l>>4) gathers row blk*256+16w+rl, cols q*8 + {0,32,64,96}
// of each conv — exactly its 8 MFMA A-fragments. 66KB LDS shared by 16 waves
// -> 2 blocks/CU = 32 waves/CU.
__global__ __launch_bounds__(1024, 8) void fused_gather_gemm(
    const int* __restrict__ off, const int2* __restrict__ csr,
    const unsigned short* __restrict__ xb, const float* __restrict__ dinv,
    const unsigned short* __restrict__ Mt, const float* __restrict__ bt,
    float* __restrict__ out) {
    __shared__ unsigned short mlds[128][264];   // +8 pad
    int t = threadIdx.x;
    for (int c = t; c < 4096; c += 1024) {
        int row = c >> 5;
        int kc = (c & 31) * 8;
        *(ulonglong2*)&mlds[row][kc] = *(const ulonglong2*)&Mt[row * 256 + kc];
    }
    __syncthreads();

    int wave = t >> 6, lane = t & 63;
    int rl = lane & 15, q = lane >> 4;
    int gr = blockIdx.x * FROWS + wave * 16 + rl;        // gathered row
    const bool valid = gr < N_NODES;

    bf16x8 af[8];
    #pragma unroll
    for (int conv = 0; conv < 2; ++conv) {
        float acc[4][8];
        if (valid) {
            int n = conv * N_NODES + gr;
            float dn = dinv[n];
            float f = dn * dn;
            const unsigned short* xr = xb + (size_t)gr * D + q * 8;
            #pragma unroll
            for (int m = 0; m < 4; ++m) {
                bf16x8 v = *(const bf16x8*)(xr + m * 32);
                #pragma unroll
                for (int j = 0; j < 8; ++j) acc[m][j] = bf2f((unsigned short)v[j]) * f;
            }
            int e0 = off[n], e1 = off[n + 1];
            if (e0 < e1) {
                int2 sc = csr[e0];                        // pipeline: entry for edge e
                for (int e = e0; e < e1; ++e) {
                    int2 nsc = (e + 1 < e1) ? csr[e + 1] : sc;
                    float coef = __int_as_float(sc.y);
                    const unsigned short* xs = xb + (size_t)sc.x * D + q * 8;
                    #pragma unroll
                    for (int m = 0; m < 4; ++m) {
                        bf16x8 v = *(const bf16x8*)(xs + m * 32);
                        #pragma unroll
                        for (int j = 0; j < 8; ++j) acc[m][j] += coef * bf2f((unsigned short)v[j]);
                    }
                    sc = nsc;
                }
            }
        } else {
            #pragma unroll
            for (int m = 0; m < 4; ++m)
                #pragma unroll
                for (int j = 0; j < 8; ++j) acc[m][j] = 0.f;
        }
        #pragma unroll
        for (int m = 0; m < 4; ++m) {
            bf16x8 a;
            #pragma unroll
            for (int j = 0; j < 8; ++j) a[j] = (short)f2bf(acc[m][j]);
            af[conv * 4 + m] = a;
        }
    }

    f32x4 C[8];
    #pragma unroll
    for (int i = 0; i < 8; ++i) C[i] = (f32x4){0.f, 0.f, 0.f, 0.f};
    #pragma unroll
    for (int ks = 0; ks < 8; ++ks) {
        bf16x8 afr = af[ks];          // ks 0..3 -> conv1 k-blocks, 4..7 -> conv2
        #pragma unroll
        for (int ct = 0; ct < 8; ++ct) {
            bf16x8 bfr = *(const bf16x8*)&mlds[ct * 16 + rl][ks * 32 + q * 8];
            C[ct] = __builtin_amdgcn_mfma_f32_16x16x32_bf16(afr, bfr, C[ct], 0, 0, 0);
        }
    }

    // C/D layout: col = lane&15, row = (lane>>4)*4 + reg
    int orow = blockIdx.x * FROWS + wave * 16 + q * 4;
    #pragma unroll
    for (int ct = 0; ct < 8; ++ct) {
        int col = ct * 16 + rl;
        float b = bt[col];
        #pragma unroll
        for (int reg = 0; reg < 4; ++reg) {
            int row = orow + reg;
            if (row < N_NODES) out[(long long)row * D + col] = C[ct][reg] + b;
        }
    }
}

extern "C" void kernel_launch(void* const* d_in, const int* in_sizes, int n_in,
                              void* d_out, int out_size, void* d_ws, size_t ws_size,
                              hipStream_t stream) {
    const float* x      = (const float*)d_in[0];
    const void*  e_pos  = d_in[1];
    const void*  e_neg  = d_in[2];
    const float* W1     = (const float*)d_in[3];
    const float* b1     = (const float*)d_in[4];
    const float* W2     = (const float*)d_in[5];
    const float* b2     = (const float*)d_in[6];
    const float* weight = (const float*)d_in[7];
    const float* bias   = (const float*)d_in[8];
    float* out = (float*)d_out;

    // ---- workspace layout (~38 MB) ----
    unsigned short* xb = (unsigned short*)d_ws;          // N*D bf16
    unsigned short* Mt = xb + (size_t)N_NODES * D;       // 128*256
    float* bt   = (float*)(Mt + 128 * 256);              // D
    float* dinv = bt + D;                                // NT
    int*   flag = (int*)(dinv + NT);                     // pad to 4 ints
    int*   degi = flag + 4;                              // NT
    int*   off  = degi + NT;                             // NT+4 (pad)
    int*   bsum = off + NT + 4;                          // 1024
    int2*  csr  = (int2*)(bsum + 1024);                  // ET

    detect_kernel<<<1, 64, 0, stream>>>((const unsigned long long*)e_pos, flag);
    hipMemsetAsync(degi, 0, NT * sizeof(int), stream);
    prep_weights<<<129, 256, 0, stream>>>(W1, W2, weight, b1, b2, bias, Mt, bt);

    const int egrid = (ET + 255) / 256;                  // 4688
    x2bf_degree<<<12500 + egrid, 256, 0, stream>>>(x, xb, e_pos, e_neg, flag, degi);
    scan_pass1<<<NBLK2, SCAN_B, 0, stream>>>(degi, bsum, dinv);
    scan_pass2<<<1, 1024, 0, stream>>>(bsum);
    scan_pass3<<<NBLK2, SCAN_B, 0, stream>>>(degi, bsum, off);
    csr_fill_both<<<egrid, 256, 0, stream>>>(e_pos, e_neg, flag, off, degi, dinv, csr);

    fused_gather_gemm<<<FBLK, 1024, 0, stream>>>(off, csr, xb, dinv, Mt, bt, out);
}

// Round 8
// 222.873 us; speedup vs baseline: 1.1948x; 1.1948x over previous
//
#include <hip/hip_runtime.h>

#define N_NODES 100000
#define NT (2 * N_NODES)             // stacked nodes (conv1 then conv2)
#define D 128
#define N_EDGES 600000
#define ET (2 * N_EDGES)
#define SCAN_B 256
#define NBLK2 ((NT + SCAN_B - 1) / SCAN_B)   // 782
#define FBLK ((N_NODES + 127) / 128)         // 782 fused blocks
#define ZBLK ((NT / 4 + 255) / 256)          // 196 blocks zero degi (int4)

typedef __attribute__((ext_vector_type(8))) short bf16x8;
typedef __attribute__((ext_vector_type(4))) float f32x4;

__device__ __forceinline__ unsigned short f2bf(float f) {
    union { float f; unsigned u; } v; v.f = f;
    unsigned r = (v.u + 0x7fff + ((v.u >> 16) & 1)) >> 16;   // RNE
    return (unsigned short)r;
}
__device__ __forceinline__ float bf2f(unsigned short h) {
    union { unsigned u; float f; } v; v.u = ((unsigned)h) << 16;
    return v.f;
}

// ---------- edge index dtype handling ----------
__device__ __forceinline__ long long load_idx(const void* e, long long i, int is32) {
    if (is32) return (long long)((const int*)e)[i];
    return ((const long long*)e)[i];
}

// ---------- merged prep: Mt (blocks 0..127) | bt + detect (block 128) | zero degi ----------
__global__ void prep_all(const float* __restrict__ W1, const float* __restrict__ W2,
                         const float* __restrict__ weight,
                         const float* __restrict__ b1, const float* __restrict__ b2,
                         const float* __restrict__ bias,
                         const unsigned long long* __restrict__ e_pos,
                         unsigned short* __restrict__ Mt, float* __restrict__ bt,
                         int* __restrict__ flag, int* __restrict__ degi) {
    if (blockIdx.x < 128) {
        // Mt[j][k] bf16: j=out col (128), k=stacked contraction (256)
        int idx = blockIdx.x * 256 + threadIdx.x;
        int j = idx >> 8, k = idx & 255;
        float a = 0.f;
        if (k < D) {
            for (int d = 0; d < D; ++d) a += W1[k * D + d] * weight[d * D + j];
        } else {
            for (int d = 0; d < D; ++d) a += W2[(k - D) * D + d] * weight[(D + d) * D + j];
        }
        Mt[j * 256 + k] = f2bf(a);
    } else if (blockIdx.x == 128) {
        int t = threadIdx.x;
        if (t < D) {
            float a = bias[t];
            for (int k = 0; k < D; ++k)
                a += b1[k] * weight[k * D + t] + b2[k] * weight[(D + k) * D + t];
            bt[t] = a;
        } else if (t < 192) {
            // edge dtype detect: wave 2 (threads 128..191) samples 64 values
            unsigned long long v = e_pos[t - 128];
            unsigned long long m = __ballot(v > 0xFFFFFFFFull);
            if (t == 128) *flag = (m != 0ull) ? 1 : 0;
        }
    } else {
        int i = (blockIdx.x - 129) * 256 + threadIdx.x;   // int4 slots
        if (i < NT / 4) ((int4*)degi)[i] = make_int4(0, 0, 0, 0);
    }
}

// ---------- merged: x->bf16 convert (blocks 0..12499) + degree histogram (rest) ----------
__global__ void x2bf_degree(const float* __restrict__ x, unsigned short* __restrict__ xb,
                            const void* __restrict__ ep, const void* __restrict__ en,
                            const int* __restrict__ flag, int* __restrict__ degi) {
    if (blockIdx.x < 12500) {
        long long t = (long long)blockIdx.x * 256 + threadIdx.x;   // N*32 float4 slots
        float4 a = ((const float4*)x)[t];
        ((ushort4*)xb)[t] = make_ushort4(f2bf(a.x), f2bf(a.y), f2bf(a.z), f2bf(a.w));
    } else {
        int i = (blockIdx.x - 12500) * 256 + threadIdx.x;
        if (i >= ET) return;
        int is32 = *flag;
        int conv = (i >= N_EDGES);
        const void* e = conv ? en : ep;
        int j = conv ? i - N_EDGES : i;
        long long d = load_idx(e, (long long)N_EDGES + j, is32);
        atomicAdd(&degi[conv * N_NODES + (int)d], 1);
    }
}

// ---------- scan pass1 over NT (+ fused dinv) ----------
__global__ void scan_pass1(const int* __restrict__ degi, int* __restrict__ bsum,
                           float* __restrict__ dinv) {
    __shared__ int sm[SCAN_B];
    int i = blockIdx.x * SCAN_B + threadIdx.x;
    int v = (i < NT) ? degi[i] : 0;
    if (i < NT) dinv[i] = rsqrtf((float)v + 1.0f);
    sm[threadIdx.x] = v;
    __syncthreads();
    for (int s = SCAN_B / 2; s > 0; s >>= 1) {
        if (threadIdx.x < s) sm[threadIdx.x] += sm[threadIdx.x + s];
        __syncthreads();
    }
    if (threadIdx.x == 0) bsum[blockIdx.x] = sm[0];
}

// ---------- scan pass3 with self-computed base (pass2 folded in) ----------
__global__ void scan_pass3(const int* __restrict__ degi, const int* __restrict__ bsum,
                           int* __restrict__ off) {
    __shared__ int red[SCAN_B];
    __shared__ int sm[SCAN_B];
    // base = sum(bsum[0..blockIdx.x))  — redundant per-block reduce (<=782 ints, L2-hot)
    int partial = 0;
    for (int i = threadIdx.x; i < blockIdx.x; i += SCAN_B) partial += bsum[i];
    red[threadIdx.x] = partial;
    __syncthreads();
    for (int s = SCAN_B / 2; s > 0; s >>= 1) {
        if (threadIdx.x < s) red[threadIdx.x] += red[threadIdx.x + s];
        __syncthreads();
    }
    int base = red[0];
    // local inclusive scan
    int i = blockIdx.x * SCAN_B + threadIdx.x;
    int v = (i < NT) ? degi[i] : 0;
    sm[threadIdx.x] = v;
    __syncthreads();
    for (int ofs = 1; ofs < SCAN_B; ofs <<= 1) {
        int add = (threadIdx.x >= ofs) ? sm[threadIdx.x - ofs] : 0;
        __syncthreads();
        sm[threadIdx.x] += add;
        __syncthreads();
    }
    int excl = sm[threadIdx.x] - v + base;
    if (i < NT) off[i] = excl;
    if (i == NT - 1) off[NT] = excl + v;
}

// ---------- CSR fill (both convs), stores {src_row, coef}; degi used as countdown ----------
__global__ void csr_fill_both(const void* __restrict__ ep, const void* __restrict__ en,
                              const int* __restrict__ flag, const int* __restrict__ off,
                              int* __restrict__ degi, const float* __restrict__ dinv,
                              int2* __restrict__ csr) {
    int i = blockIdx.x * blockDim.x + threadIdx.x;
    if (i >= ET) return;
    int is32 = *flag;
    int conv = (i >= N_EDGES);
    const void* e = conv ? en : ep;
    int j = conv ? i - N_EDGES : i;
    int si = (int)load_idx(e, j, is32);
    int di = (int)load_idx(e, (long long)N_EDGES + j, is32);
    int g = conv * N_NODES;
    int node = g + di;
    int pos = off[node] + atomicSub(&degi[node], 1) - 1;   // countdown: positions deg-1..0
    float coef = dinv[g + si] * dinv[node];
    csr[pos] = make_int2(si, __float_as_int(coef));
}

// ---------- fused gather + GEMM (R6-proven shape: 512 thr, 56 VGPR, no spill) ----------
// 8 waves; wave w owns output rows [blk*128 + 16w, +16).
// Lane l (rl=l&15, q=l>>4) gathers row blk*128+16w+rl, cols q*8 + {0,32,64,96}
// of each conv — exactly its 8 MFMA A-fragments.
__global__ __launch_bounds__(512) void fused_gather_gemm(
    const int* __restrict__ off, const int2* __restrict__ csr,
    const unsigned short* __restrict__ xb, const float* __restrict__ dinv,
    const unsigned short* __restrict__ Mt, const float* __restrict__ bt,
    float* __restrict__ out) {
    __shared__ unsigned short mlds[128][264];   // +8 pad: 2-way bank alias only (free)
    int t = threadIdx.x;
    for (int c = t; c < 4096; c += 512) {
        int row = c >> 5;
        int kc = (c & 31) * 8;
        *(ulonglong2*)&mlds[row][kc] = *(const ulonglong2*)&Mt[row * 256 + kc];
    }
    __syncthreads();

    int wave = t >> 6, lane = t & 63;
    int rl = lane & 15, q = lane >> 4;
    int gr = blockIdx.x * 128 + wave * 16 + rl;          // gathered row
    const bool valid = gr < N_NODES;

    bf16x8 af[8];
    #pragma unroll
    for (int conv = 0; conv < 2; ++conv) {
        float acc[4][8];
        if (valid) {
            int n = conv * N_NODES + gr;
            float dn = dinv[n];
            float f = dn * dn;
            const unsigned short* xr = xb + (size_t)gr * D + q * 8;
            #pragma unroll
            for (int m = 0; m < 4; ++m) {
                bf16x8 v = *(const bf16x8*)(xr + m * 32);
                #pragma unroll
                for (int j = 0; j < 8; ++j) acc[m][j] = bf2f((unsigned short)v[j]) * f;
            }
            int e0 = off[n], e1 = off[n + 1];
            for (int e = e0; e < e1; ++e) {
                int2 sc = csr[e];
                float coef = __int_as_float(sc.y);
                const unsigned short* xs = xb + (size_t)sc.x * D + q * 8;
                #pragma unroll
                for (int m = 0; m < 4; ++m) {
                    bf16x8 v = *(const bf16x8*)(xs + m * 32);
                    #pragma unroll
                    for (int j = 0; j < 8; ++j) acc[m][j] += coef * bf2f((unsigned short)v[j]);
                }
            }
        } else {
            #pragma unroll
            for (int m = 0; m < 4; ++m)
                #pragma unroll
                for (int j = 0; j < 8; ++j) acc[m][j] = 0.f;
        }
        #pragma unroll
        for (int m = 0; m < 4; ++m) {
            bf16x8 a;
            #pragma unroll
            for (int j = 0; j < 8; ++j) a[j] = (short)f2bf(acc[m][j]);
            af[conv * 4 + m] = a;
        }
    }

    f32x4 C[8];
    #pragma unroll
    for (int i = 0; i < 8; ++i) C[i] = (f32x4){0.f, 0.f, 0.f, 0.f};
    #pragma unroll
    for (int ks = 0; ks < 8; ++ks) {
        bf16x8 afr = af[ks];          // ks 0..3 -> conv1 k-blocks, 4..7 -> conv2
        #pragma unroll
        for (int ct = 0; ct < 8; ++ct) {
            bf16x8 bfr = *(const bf16x8*)&mlds[ct * 16 + rl][ks * 32 + q * 8];
            C[ct] = __builtin_amdgcn_mfma_f32_16x16x32_bf16(afr, bfr, C[ct], 0, 0, 0);
        }
    }

    // C/D layout: col = lane&15, row = (lane>>4)*4 + reg
    int orow = blockIdx.x * 128 + wave * 16 + q * 4;
    #pragma unroll
    for (int ct = 0; ct < 8; ++ct) {
        int col = ct * 16 + rl;
        float b = bt[col];
        #pragma unroll
        for (int reg = 0; reg < 4; ++reg) {
            int row = orow + reg;
            if (row < N_NODES) out[(long long)row * D + col] = C[ct][reg] + b;
        }
    }
}

extern "C" void kernel_launch(void* const* d_in, const int* in_sizes, int n_in,
                              void* d_out, int out_size, void* d_ws, size_t ws_size,
                              hipStream_t stream) {
    const float* x      = (const float*)d_in[0];
    const void*  e_pos  = d_in[1];
    const void*  e_neg  = d_in[2];
    const float* W1     = (const float*)d_in[3];
    const float* b1     = (const float*)d_in[4];
    const float* W2     = (const float*)d_in[5];
    const float* b2     = (const float*)d_in[6];
    const float* weight = (const float*)d_in[7];
    const float* bias   = (const float*)d_in[8];
    float* out = (float*)d_out;

    // ---- workspace layout (~38 MB) ----
    unsigned short* xb = (unsigned short*)d_ws;          // N*D bf16
    unsigned short* Mt = xb + (size_t)N_NODES * D;       // 128*256
    float* bt   = (float*)(Mt + 128 * 256);              // D
    float* dinv = bt + D;                                // NT
    int*   flag = (int*)(dinv + NT);                     // pad to 4 ints
    int*   degi = flag + 4;                              // NT (16B aligned)
    int*   off  = degi + NT;                             // NT+4 (pad)
    int*   bsum = off + NT + 4;                          // 1024
    int2*  csr  = (int2*)(bsum + 1024);                  // ET

    // A: Mt | bt+detect | zero degi     (1 dispatch replaces 4)
    prep_all<<<129 + ZBLK, 256, 0, stream>>>(W1, W2, weight, b1, b2, bias,
                                             (const unsigned long long*)e_pos,
                                             Mt, bt, flag, degi);
    // B: x->bf16 + degree histogram
    const int egrid = (ET + 255) / 256;                  // 4688
    x2bf_degree<<<12500 + egrid, 256, 0, stream>>>(x, xb, e_pos, e_neg, flag, degi);
    // C/D: scan (pass2 folded into pass3)
    scan_pass1<<<NBLK2, SCAN_B, 0, stream>>>(degi, bsum, dinv);
    scan_pass3<<<NBLK2, SCAN_B, 0, stream>>>(degi, bsum, off);
    // E: CSR fill
    csr_fill_both<<<egrid, 256, 0, stream>>>(e_pos, e_neg, flag, off, degi, dinv, csr);
    // F: fused gather + GEMM
    fused_gather_gemm<<<FBLK, 512, 0, stream>>>(off, csr, xb, dinv, Mt, bt, out);
}